// Round 10
// baseline (325.744 us; speedup 1.0000x reference)
//
#include <hip/hip_runtime.h>
#include <hip/hip_bf16.h>
#include <stdint.h>

// Problem constants
#define Bq 1024
#define Dq 512
#define Nq 16
#define Hq 512
#define Mq (Bq*Nq)   // 16384

typedef short v8s  __attribute__((ext_vector_type(8)));
typedef float v4f  __attribute__((ext_vector_type(4)));

typedef __attribute__((address_space(3))) unsigned int as3_u32;
typedef __attribute__((address_space(1))) const unsigned int as1_u32;

__device__ __forceinline__ unsigned short f2bf(float f) {
  union { float f; unsigned u; } v; v.f = f;
  return (unsigned short)((v.u + 0x7fffu + ((v.u >> 16) & 1u)) >> 16);
}

// Merged prep (R6 version, audited): blocks [0,1024) transpose x;
// blocks [1024, 1024+18*256) transpose the 18 weight matrices.
// x: Xb[b*16+n][d] = bf16(x[b][d][n]);  w: out[z][c][r] = bf16(in[z][r][c]).
__global__ void k_prep(const float* __restrict__ x,
                       const float* __restrict__ Ws1, const float* __restrict__ Ws2,
                       const float* __restrict__ Wc1,
                       unsigned short* __restrict__ xb,
                       unsigned short* __restrict__ Ws1t, unsigned short* __restrict__ Ws2t,
                       unsigned short* __restrict__ Wc1t) {
  const int bid = blockIdx.x;
  const int t = threadIdx.x;
  if (bid < Bq) {
    __shared__ float lds[Dq][Nq + 1];
    const float* xi = x + (size_t)bid * Dq * Nq;
    for (int p = 0; p < (Dq*Nq)/256; ++p) {
      int i = t + p*256;
      lds[i >> 4][i & (Nq-1)] = xi[i];
    }
    __syncthreads();
    unsigned short* o = xb + (size_t)bid * Nq * Dq;
    for (int p = 0; p < (Dq*Nq)/256; ++p) {
      int i = t + p*256;
      o[i] = f2bf(lds[i & (Dq-1)][i >> 9]);   // i = n*512 + d
    }
  } else {
    __shared__ float tile[32][33];
    const int r = bid - Bq;
    const int z = r >> 8;                 // 18 z-slices, 256 blocks each
    const int rem = r & 255;
    const int bx = rem & 15, by = rem >> 4;
    const float* in;
    unsigned short* out;
    if (z == 0)      { in = Ws1; out = Ws1t; }
    else if (z == 1) { in = Ws2; out = Ws2t; }
    else             { in = Wc1 + (size_t)(z-2) * 512 * 512; out = Wc1t + (size_t)(z-2) * 512 * 512; }
    const int tx = t & 31, ty = t >> 5;   // (32,8)
    const int c0 = bx * 32, r0 = by * 32;
#pragma unroll
    for (int j = 0; j < 4; ++j)
      tile[ty + j*8][tx] = in[(size_t)(r0 + ty + j*8) * 512 + c0 + tx];
    __syncthreads();
#pragma unroll
    for (int j = 0; j < 4; ++j) {
      int c = c0 + ty + j*8;
      int rr = r0 + tx;
      out[(size_t)c * 512 + rr] = f2bf(tile[tx][ty + j*8]);
    }
  }
}

// ---------------------------------------------------------------------------
// Shared-MLP GEMM in the R9-winning class: 128x256 tile, 256 threads =
// 4 waves (2x2) of 64x128, 16x16x32 fragments (zero-conflict chunk-XOR
// swizzle), BK=32 double-buffered with prefetch-before-compute, one barrier
// per K-step.  out = lrelu(A@Bt^T + bias) stored bf16; permute remaps the
// output row grow -> (grow&15)*Bq + (grow>>4) (m = n*B + b order).
// Replaces the old 32x32-fragment MODE0 kernel (1.26e7-conflict class).
// ---------------------------------------------------------------------------
__global__ __launch_bounds__(256, 2)
void k_gemm2(const unsigned short* __restrict__ A,
             const unsigned short* __restrict__ Bt,
             const float* __restrict__ bias,
             unsigned short* __restrict__ O,
             int permute) {
  __shared__ __align__(16) unsigned short As[2][128][32];
  __shared__ __align__(16) unsigned short Bs[2][256][32];

  const int t = threadIdx.x;
  const int wave = t >> 6, lane = t & 63;
  const int wr = wave >> 1, wc = wave & 1;         // 2x2 waves of 64x128
  const int fr = lane & 15, fq = lane >> 4;

  const int bm = blockIdx.x * 128;
  const int bn = blockIdx.y * 256;

  // Staging (R9-verified lane math for 64B rows): lane l -> row l>>2,
  // 16B slot l&3; source chunk pre-XORed with read swizzle ((row>>1)&3).
  const int sr = lane >> 2;
  const int sc = (lane & 3) ^ ((sr >> 1) & 3);
  const unsigned short* aSrc = A  + (size_t)(bm + wave*32 + sr) * Dq + sc*8;
  const unsigned short* bSrc = Bt + (size_t)(bn + wave*64 + sr) * Dq + sc*8;

  auto stage = [&](int buf, int kt) {
#pragma unroll
    for (int j = 0; j < 2; ++j)
      __builtin_amdgcn_global_load_lds((as1_u32*)(aSrc + kt*32 + (size_t)j*16*Dq),
                                       (as3_u32*)&As[buf][wave*32 + j*16][0], 16, 0, 0);
#pragma unroll
    for (int j = 0; j < 4; ++j)
      __builtin_amdgcn_global_load_lds((as1_u32*)(bSrc + kt*32 + (size_t)j*16*Dq),
                                       (as3_u32*)&Bs[buf][wave*64 + j*16][0], 16, 0, 0);
  };

  const int swz = (fq ^ ((fr >> 1) & 3)) * 16;
  int offA[4], offB[8];
#pragma unroll
  for (int mi = 0; mi < 4; ++mi) offA[mi] = (wr*64  + mi*16 + fr) * 64 + swz;
#pragma unroll
  for (int ni = 0; ni < 8; ++ni) offB[ni] = (wc*128 + ni*16 + fr) * 64 + swz;

  v4f acc[4][8] = {};

  stage(0, 0);
  __syncthreads();

  for (int kt = 0; kt < 16; ++kt) {
    const int cur = kt & 1;
    if (kt + 1 < 16) stage(cur ^ 1, kt + 1);

    const char* aB = (const char*)&As[cur][0][0];
    const char* bB = (const char*)&Bs[cur][0][0];
    v8s af[4], bf[8];
#pragma unroll
    for (int mi = 0; mi < 4; ++mi) af[mi] = *(const v8s*)(aB + offA[mi]);
#pragma unroll
    for (int ni = 0; ni < 8; ++ni) bf[ni] = *(const v8s*)(bB + offB[ni]);
#pragma unroll
    for (int mi = 0; mi < 4; ++mi)
#pragma unroll
      for (int ni = 0; ni < 8; ++ni)
        acc[mi][ni] = __builtin_amdgcn_mfma_f32_16x16x32_bf16(af[mi], bf[ni], acc[mi][ni], 0, 0, 0);

    __syncthreads();
  }

  // Epilogue: lrelu + bias, bf16 store.  D-frag: col=l&15, row=(l>>4)*4+reg.
  float bcol[8];
#pragma unroll
  for (int ni = 0; ni < 8; ++ni) bcol[ni] = bias[bn + wc*128 + ni*16 + fr];
#pragma unroll
  for (int mi = 0; mi < 4; ++mi) {
#pragma unroll
    for (int reg = 0; reg < 4; ++reg) {
      int grow = bm + wr*64 + mi*16 + fq*4 + reg;
      int orow = permute ? ((grow & 15) * Bq + (grow >> 4)) : grow;
#pragma unroll
      for (int ni = 0; ni < 8; ++ni) {
        int col = bn + wc*128 + ni*16 + fr;
        float v = acc[mi][ni][reg] + bcol[ni];
        v = v >= 0.f ? v : 0.1f * v;
        O[(size_t)orow * 512 + col] = f2bf(v);
      }
    }
  }
}

// ---------------------------------------------------------------------------
// Head-GEMM (VERBATIM R9, session best: 200.4us, MfmaUtil 29.6, 0 conflicts).
// 128x256 tile, 256 threads = 4 waves (2x2) of 64x128 each, acc[4][8] v4f.
// BK=32 dbuf, prefetch-before-compute, one barrier per K-step, natural
// dispatch order, 16x16x32 fragments, zero-conflict chunk-XOR swizzle.
// ---------------------------------------------------------------------------
__global__ __launch_bounds__(256, 2)
void k_headgemm(const unsigned short* __restrict__ A,
                const unsigned short* __restrict__ Bt,
                const float* __restrict__ bias,
                float* __restrict__ FL,
                const float* __restrict__ w2) {
  __shared__ __align__(16) unsigned short As[2][128][32];
  __shared__ __align__(16) unsigned short Bs[2][256][32];

  const int t = threadIdx.x;
  const int wave = t >> 6, lane = t & 63;
  const int wr = wave >> 1, wc = wave & 1;         // 2x2 waves of 64x128
  const int fr = lane & 15, fq = lane >> 4;

  const int bm = blockIdx.x * 128;
  const int bn = blockIdx.y * 256;
  const int z  = blockIdx.z;

  const unsigned short* Bz = Bt + (size_t)z * Dq * 512;
  const float* biasz = bias + (size_t)z * 512;
  const float* w2z   = w2   + (size_t)z * 512;

  const int sr = lane >> 2;
  const int sc = (lane & 3) ^ ((sr >> 1) & 3);
  const unsigned short* aSrc = A  + (size_t)(bm + wave*32 + sr) * Dq + sc*8;
  const unsigned short* bSrc = Bz + (size_t)(bn + wave*64 + sr) * Dq + sc*8;

  auto stage = [&](int buf, int kt) {
#pragma unroll
    for (int j = 0; j < 2; ++j)
      __builtin_amdgcn_global_load_lds((as1_u32*)(aSrc + kt*32 + (size_t)j*16*Dq),
                                       (as3_u32*)&As[buf][wave*32 + j*16][0], 16, 0, 0);
#pragma unroll
    for (int j = 0; j < 4; ++j)
      __builtin_amdgcn_global_load_lds((as1_u32*)(bSrc + kt*32 + (size_t)j*16*Dq),
                                       (as3_u32*)&Bs[buf][wave*64 + j*16][0], 16, 0, 0);
  };

  const int swz = (fq ^ ((fr >> 1) & 3)) * 16;
  int offA[4], offB[8];
#pragma unroll
  for (int mi = 0; mi < 4; ++mi) offA[mi] = (wr*64  + mi*16 + fr) * 64 + swz;
#pragma unroll
  for (int ni = 0; ni < 8; ++ni) offB[ni] = (wc*128 + ni*16 + fr) * 64 + swz;

  v4f acc[4][8] = {};

  stage(0, 0);
  __syncthreads();                 // prologue drain: tile 0 resident

  for (int kt = 0; kt < 16; ++kt) {
    const int cur = kt & 1;
    if (kt + 1 < 16) stage(cur ^ 1, kt + 1);   // prefetch flies during compute

    const char* aB = (const char*)&As[cur][0][0];
    const char* bB = (const char*)&Bs[cur][0][0];
    v8s af[4], bf[8];
#pragma unroll
    for (int mi = 0; mi < 4; ++mi) af[mi] = *(const v8s*)(aB + offA[mi]);
#pragma unroll
    for (int ni = 0; ni < 8; ++ni) bf[ni] = *(const v8s*)(bB + offB[ni]);
#pragma unroll
    for (int mi = 0; mi < 4; ++mi)
#pragma unroll
      for (int ni = 0; ni < 8; ++ni)
        acc[mi][ni] = __builtin_amdgcn_mfma_f32_16x16x32_bf16(af[mi], bf[ni], acc[mi][ni], 0, 0, 0);

    __syncthreads();               // closes reads of cur + drains prefetch
  }

  // Epilogue: lrelu + Wc2 dot over this wave's 128 cols, 16-lane reduce,
  // atomicAdd into FL[m][z].  D-frag: col=l&15, row=(l>>4)*4+reg.
  float bcol[8], wcol[8];
#pragma unroll
  for (int ni = 0; ni < 8; ++ni) {
    int col = bn + wc*128 + ni*16 + fr;
    bcol[ni] = biasz[col];
    wcol[ni] = w2z[col];
  }
#pragma unroll
  for (int mi = 0; mi < 4; ++mi) {
#pragma unroll
    for (int reg = 0; reg < 4; ++reg) {
      float s = 0.f;
#pragma unroll
      for (int ni = 0; ni < 8; ++ni) {
        float v = acc[mi][ni][reg] + bcol[ni];
        v = v >= 0.f ? v : 0.1f * v;
        s += v * wcol[ni];
      }
#pragma unroll
      for (int off = 1; off < 16; off <<= 1)
        s += __shfl_xor(s, off, 64);
      if (fr == 0) {
        int grow = bm + wr*64 + mi*16 + fq*4 + reg;
        atomicAdd(&FL[(size_t)grow * Nq + z], s);
      }
    }
  }
}

// full_out[m][n] = FL[m][n] + bc2[n]; out[b][n] = sigmoid(full_out[n*B+b][n])
__global__ void k_final(const float* __restrict__ fl, const float* __restrict__ bc2,
                        float* __restrict__ out) {
  int i = blockIdx.x * 256 + threadIdx.x;
  int m = i >> 4, n = i & 15;
  float v = fl[i] + bc2[n];
  out[Mq + i] = v;
  if (n == (m >> 10)) {
    int b = m & (Bq - 1);
    out[b * Nq + n] = 1.f / (1.f + __expf(-v));
  }
}

extern "C" void kernel_launch(void* const* d_in, const int* in_sizes, int n_in,
                              void* d_out, int out_size, void* d_ws, size_t ws_size,
                              hipStream_t stream) {
  (void)in_sizes; (void)n_in; (void)out_size; (void)ws_size;
  const float* x   = (const float*)d_in[0];
  const float* Ws1 = (const float*)d_in[1];
  const float* bs1 = (const float*)d_in[2];
  const float* Ws2 = (const float*)d_in[3];
  const float* bs2 = (const float*)d_in[4];
  const float* Wc1 = (const float*)d_in[5];
  const float* bc1 = (const float*)d_in[6];
  const float* Wc2 = (const float*)d_in[7];
  const float* bc2 = (const float*)d_in[8];

  char* ws = (char*)d_ws;
  unsigned short* Xb   = (unsigned short*)(ws);
  unsigned short* Hbuf = (unsigned short*)(ws + (size_t)16*1024*1024);
  unsigned short* Sm   = (unsigned short*)(ws + (size_t)32*1024*1024);
  unsigned short* Ws1t = (unsigned short*)(ws + (size_t)48*1024*1024);
  unsigned short* Ws2t = (unsigned short*)(ws + (size_t)48*1024*1024 + 512*1024);
  unsigned short* Wc1t = (unsigned short*)(ws + (size_t)49*1024*1024);
  float*          FL   = (float*)         (ws + (size_t)57*1024*1024);

  hipMemsetAsync(FL, 0, (size_t)Mq * Nq * sizeof(float), stream);

  // merged transposes: 1024 x-blocks + 18*256 w-blocks
  k_prep<<<Bq + 18*256, 256, 0, stream>>>(x, Ws1, Ws2, Wc1, Xb, Ws1t, Ws2t, Wc1t);

  // shared MLP in the R9-class structure:
  // H = lrelu(Xb@Ws1+bs1); Sm = lrelu(H@Ws2+bs2) in m = n*B+b row order
  k_gemm2<<<dim3(128,2), 256, 0, stream>>>(Xb,   Ws1t, bs1, Hbuf, 0);
  k_gemm2<<<dim3(128,2), 256, 0, stream>>>(Hbuf, Ws2t, bs2, Sm,   1);
  // fused per-head GEMM + H-reduction into FL (R9 verbatim)
  k_headgemm<<<dim3(128,2,16), 256, 0, stream>>>(Sm, Wc1t, bc1, FL, Wc2);

  k_final<<<(Mq*Nq)/256, 256, 0, stream>>>(FL, bc2, (float*)d_out);
}